// Round 1
// baseline (1147.596 us; speedup 1.0000x reference)
//
#include <hip/hip_runtime.h>

typedef __attribute__((ext_vector_type(8))) short short8;
typedef __attribute__((ext_vector_type(4))) float floatx4;
typedef __attribute__((ext_vector_type(8))) unsigned short ushort8;

#define FOUT 18688
#define FFI  8192

__device__ __forceinline__ float b2f(unsigned short u){
  union { unsigned int i; float f; } v; v.i = ((unsigned int)u) << 16; return v.f;
}
__device__ __forceinline__ unsigned short f2b(float f){
  union { float f; unsigned int i; } v; v.f = f;
  unsigned int r = v.i + 0x7FFFu + ((v.i >> 16) & 1u);
  return (unsigned short)(r >> 16);
}
__device__ __forceinline__ void gld_lds16(const void* g, void* l){
  __builtin_amdgcn_global_load_lds((const __attribute__((address_space(1))) void*)g,
                                   (__attribute__((address_space(3))) void*)l, 16, 0, 0);
}

// ---------------- LayerNorm (fp32 in) -> bf16 xn ----------------
__global__ __launch_bounds__(256) void ln_kernel(const float* __restrict__ x,
                                                 const float* __restrict__ gamma,
                                                 unsigned short* __restrict__ xn){
  int row = blockIdx.x;
  const float* xr = x + (size_t)row * 2048;
  int tid = threadIdx.x;
  float v[8]; float s = 0.f, s2 = 0.f;
#pragma unroll
  for(int i=0;i<8;i++){ float t = xr[tid + i*256]; v[i]=t; s+=t; s2+=t*t; }
#pragma unroll
  for(int off=32; off>=1; off>>=1){ s += __shfl_down(s, off, 64); s2 += __shfl_down(s2, off, 64); }
  __shared__ float red[8];
  int wv = tid>>6, ln_ = tid&63;
  if(ln_==0){ red[wv] = s; red[wv+4] = s2; }
  __syncthreads();
  s  = red[0]+red[1]+red[2]+red[3];
  s2 = red[4]+red[5]+red[6]+red[7];
  float mu  = s * (1.f/2048.f);
  float var = s2 * (1.f/2048.f) - mu*mu;
  float rstd = rsqrtf(var + 1e-5f);
#pragma unroll
  for(int i=0;i<8;i++){
    float o = (v[i]-mu)*rstd*gamma[tid + i*256];
    xn[(size_t)row*2048 + tid + i*256] = f2b(o);
  }
}

// ---------------- fp32 RxC -> bf16 CxR transpose (weights) ----------------
__global__ void tcast_kernel(const float* __restrict__ W, unsigned short* __restrict__ Wt,
                             int R, int C){
  __shared__ float t[32][33];
  int bx = blockIdx.x*32, by = blockIdx.y*32;
  int tx = threadIdx.x, ty = threadIdx.y;
#pragma unroll
  for(int i=0;i<4;i++) t[ty+i*8][tx] = W[(size_t)(by+ty+i*8)*C + bx+tx];
  __syncthreads();
#pragma unroll
  for(int i=0;i<4;i++) Wt[(size_t)(bx+ty+i*8)*R + by+tx] = f2b(t[tx][ty+i*8]);
}

// ---------------- V slice of proj -> Vt[b][d][n] (bf16) ----------------
__global__ void vtrans_kernel(const unsigned short* __restrict__ proj, unsigned short* __restrict__ vt){
  __shared__ unsigned short t[32][33];
  int b = blockIdx.z;
  int n0 = blockIdx.x*32, d0 = blockIdx.y*32;
  int tx = threadIdx.x, ty = threadIdx.y;
#pragma unroll
  for(int i=0;i<4;i++) t[ty+i*8][tx] = proj[(size_t)(b*2048 + n0+ty+i*8)*FOUT + 2176 + d0+tx];
  __syncthreads();
#pragma unroll
  for(int i=0;i<4;i++) vt[((size_t)b*128 + d0+ty+i*8)*2048 + n0+tx] = t[tx][ty+i*8];
}

// ---------------- RoPE (xpos) in-place on q heads + k ----------------
__global__ __launch_bounds__(256) void rope_kernel(unsigned short* __restrict__ proj){
  int row = blockIdx.x;          // b*2048 + i
  int i = row & 2047;
  unsigned short* pr = proj + (size_t)row*FOUT;
  float fi = (float)i;
  float pw0 = (fi - 1024.f) * (1.f/512.f);
  for(int item = threadIdx.x; item < 17*64; item += 256){
    int slot = item >> 6;        // 0..15 = q head, 16 = k
    int j = item & 63;
    float fj = (float)j;
    float invf = powf(10000.f, -fj*(1.f/64.f));
    float p = fi * invf;
    float c = cosf(p), sn = sinf(p);
    float sv = (2.f*fj + 51.2f) * (1.f/179.2f);
    float pw = (slot==16) ? -pw0 : pw0;
    float scale = powf(sv, pw);
    int colbase = (slot<16) ? slot*128 : 2048;
    float x1 = b2f(pr[colbase+j]);
    float x2 = b2f(pr[colbase+j+64]);
    float cs = c*scale, ss = sn*scale;
    pr[colbase+j]    = f2b(x1*cs - x2*ss);
    pr[colbase+j+64] = f2b(x2*cs + x1*ss);
  }
}

// ---------------- bf16 GEMM: C(MxN) = A(MxK) * Bt(NxK)^T ----------------
// m97 structure: 128x128 tile, BK=32, 4 waves (2x2 of 64x64), global_load_lds w16,
// linear LDS + pre-swizzled global source (chunk ^= (row>>1)&3) for ~2-way conflicts.
// MODE 0: store bf16 into Cb. MODE 1: Cf = v. MODE 2: Cf += v.
template<int MODE>
__global__ __launch_bounds__(256) void gemm_kernel(const unsigned short* __restrict__ A,
                                                   const unsigned short* __restrict__ Bt,
                                                   unsigned short* __restrict__ Cb,
                                                   float* __restrict__ Cf,
                                                   int M, int N, int K){
  __shared__ unsigned short lA[128*32];
  __shared__ unsigned short lB[128*32];
  int tid = threadIdx.x;
  int wave = tid>>6, lane = tid&63;
  int l15 = lane&15, l4 = lane>>4;
  int wr = wave>>1, wc = wave&1;
  size_t arow0 = (size_t)blockIdx.y*128;
  size_t brow0 = (size_t)blockIdx.x*128;
  floatx4 acc[4][4];
#pragma unroll
  for(int m=0;m<4;m++)
#pragma unroll
    for(int n=0;n<4;n++) acc[m][n] = (floatx4)0.f;

  int f0 = tid, f1 = 256+tid;
  int ra0 = f0>>2, ca0 = (f0&3) ^ ((ra0>>1)&3);
  int ra1 = f1>>2, ca1 = (f1&3) ^ ((ra1>>1)&3);
  unsigned short* lpa0 = &lA[(wave*64)*8];
  unsigned short* lpa1 = &lA[(256+wave*64)*8];
  unsigned short* lpb0 = &lB[(wave*64)*8];
  unsigned short* lpb1 = &lB[(256+wave*64)*8];
  const unsigned short* Ab = A  + arow0*K;
  const unsigned short* Bb = Bt + brow0*K;

  for(int k0=0; k0<K; k0+=32){
    gld_lds16(Ab + (size_t)ra0*K + k0 + ca0*8, lpa0);
    gld_lds16(Ab + (size_t)ra1*K + k0 + ca1*8, lpa1);
    gld_lds16(Bb + (size_t)ra0*K + k0 + ca0*8, lpb0);
    gld_lds16(Bb + (size_t)ra1*K + k0 + ca1*8, lpb1);
    __syncthreads();
    short8 af[4], bfr[4];
#pragma unroll
    for(int m=0;m<4;m++){
      int r = wr*64 + m*16 + l15;
      int pc = l4 ^ ((r>>1)&3);
      af[m] = *(const short8*)&lA[r*32 + pc*8];
    }
#pragma unroll
    for(int n=0;n<4;n++){
      int r = wc*64 + n*16 + l15;
      int pc = l4 ^ ((r>>1)&3);
      bfr[n] = *(const short8*)&lB[r*32 + pc*8];
    }
#pragma unroll
    for(int m=0;m<4;m++)
#pragma unroll
      for(int n=0;n<4;n++)
        acc[m][n] = __builtin_amdgcn_mfma_f32_16x16x32_bf16(af[m], bfr[n], acc[m][n], 0, 0, 0);
    __syncthreads();
  }
#pragma unroll
  for(int m=0;m<4;m++){
#pragma unroll
    for(int n=0;n<4;n++){
#pragma unroll
      for(int r=0;r<4;r++){
        size_t row = arow0 + wr*64 + m*16 + l4*4 + r;
        size_t col = brow0 + wc*64 + n*16 + l15;
        float v = acc[m][n][r];
        if(MODE==0)      Cb[row*N + col] = f2b(v);
        else if(MODE==1) Cf[row*N + col] = v;
        else             Cf[row*N + col] += v;
      }
    }
  }
}

// ---------------- flash causal attention (MQA: shared K/V) ----------------
// block = (qt, head, batch); 4 waves x 16 q-rows; KV tiles of 64.
__global__ __launch_bounds__(256) void attn_kernel(const unsigned short* __restrict__ proj,
                                                   const unsigned short* __restrict__ vt,
                                                   unsigned short* __restrict__ ao){
  __shared__ unsigned short lK[64*128];   // [key][d], chunk-swizzled
  __shared__ unsigned short lV[128*64];   // [d][key], chunk-swizzled
  __shared__ unsigned short lP[4*16*64];  // per-wave P, chunk-swizzled
  int qt = blockIdx.x, hh = blockIdx.y, b = blockIdx.z;
  int tid = threadIdx.x, wave = tid>>6, lane = tid&63;
  int l15 = lane&15, l4 = lane>>4;
  int q0 = qt*64;
  int qrow = q0 + wave*16 + l15;
  const unsigned short* qp = proj + (size_t)(b*2048 + qrow)*FOUT + hh*128 + l4*8;
  short8 qf[4];
#pragma unroll
  for(int ds=0; ds<4; ds++) qf[ds] = *(const short8*)(qp + ds*32);
  floatx4 po[8];
#pragma unroll
  for(int dt=0; dt<8; dt++) po[dt] = (floatx4)0.f;
  float mrun[4] = {-1e30f,-1e30f,-1e30f,-1e30f};
  float lrun[4] = {0.f,0.f,0.f,0.f};
  unsigned short* lPw = lP + wave*1024;
  const unsigned short* kb = proj + (size_t)(b*2048)*FOUT + 2048;
  const unsigned short* vb = vt + (size_t)b*128*2048;

  for(int kv=0; kv<=qt; kv++){
    int kv0 = kv*64;
#pragma unroll
    for(int it=0; it<4; it++){
      int f = it*256 + tid;
      int r = f>>4, pc = f&15;
      int gc = pc ^ (r&7);
      gld_lds16(kb + (size_t)(kv0 + r)*FOUT + gc*8, &lK[(it*256 + wave*64)*8]);
    }
#pragma unroll
    for(int it=0; it<4; it++){
      int f = it*256 + tid;
      int d = f>>3, pc = f&7;
      int gc = pc ^ (d&7);
      gld_lds16(vb + (size_t)d*2048 + kv0 + gc*8, &lV[(it*256 + wave*64)*8]);
    }
    __syncthreads();
    floatx4 sa[4];
#pragma unroll
    for(int jt=0;jt<4;jt++) sa[jt] = (floatx4)0.f;
#pragma unroll
    for(int jt=0;jt<4;jt++){
      int krow = jt*16 + l15;
#pragma unroll
      for(int ds=0; ds<4; ds++){
        int pc = (l4 + ds*4) ^ (krow&7);
        short8 kf = *(const short8*)&lK[krow*128 + pc*8];
        sa[jt] = __builtin_amdgcn_mfma_f32_16x16x32_bf16(qf[ds], kf, sa[jt], 0,0,0);
      }
    }
    float pv[4][4];
    bool diag = (kv == qt);
#pragma unroll
    for(int jt=0;jt<4;jt++){
#pragma unroll
      for(int r=0;r<4;r++){
        float s = sa[jt][r] * 0.08838834764831843f;
        if(diag && (kv0 + jt*16 + l15 > q0 + wave*16 + l4*4 + r)) s = -1e30f;
        pv[jt][r] = s;
      }
    }
    float mnew[4], corr[4];
#pragma unroll
    for(int r=0;r<4;r++){
      float mx = fmaxf(fmaxf(pv[0][r],pv[1][r]),fmaxf(pv[2][r],pv[3][r]));
      mx = fmaxf(mx, __shfl_xor(mx, 1, 64));
      mx = fmaxf(mx, __shfl_xor(mx, 2, 64));
      mx = fmaxf(mx, __shfl_xor(mx, 4, 64));
      mx = fmaxf(mx, __shfl_xor(mx, 8, 64));
      float mn = fmaxf(mrun[r], mx);
      corr[r] = __expf(mrun[r] - mn);
      mrun[r] = mn;
      mnew[r] = mn;
    }
    float rsum[4] = {0.f,0.f,0.f,0.f};
#pragma unroll
    for(int jt=0;jt<4;jt++){
#pragma unroll
      for(int r=0;r<4;r++){
        float p = __expf(pv[jt][r] - mnew[r]);
        pv[jt][r] = p;
        rsum[r] += p;
      }
    }
#pragma unroll
    for(int r=0;r<4;r++){
      float rs = rsum[r];
      rs += __shfl_xor(rs, 1, 64);
      rs += __shfl_xor(rs, 2, 64);
      rs += __shfl_xor(rs, 4, 64);
      rs += __shfl_xor(rs, 8, 64);
      lrun[r] = lrun[r]*corr[r] + rs;
    }
#pragma unroll
    for(int dt=0;dt<8;dt++){
#pragma unroll
      for(int r=0;r<4;r++) po[dt][r] *= corr[r];
    }
#pragma unroll
    for(int jt=0;jt<4;jt++){
#pragma unroll
      for(int r=0;r<4;r++){
        int i_ = l4*4 + r;
        int j = jt*16 + l15;
        int pc = (j>>3) ^ (i_&7);
        lPw[i_*64 + pc*8 + (j&7)] = f2b(pv[jt][r]);
      }
    }
    asm volatile("s_waitcnt lgkmcnt(0)" ::: "memory");
    short8 pf[2];
#pragma unroll
    for(int ks=0;ks<2;ks++){
      int pc = (l4 + ks*4) ^ (l15&7);
      pf[ks] = *(const short8*)&lPw[l15*64 + pc*8];
    }
#pragma unroll
    for(int dt=0;dt<8;dt++){
      int d = dt*16 + l15;
#pragma unroll
      for(int ks=0;ks<2;ks++){
        int pc = (ks*4 + l4) ^ (d&7);
        short8 vf = *(const short8*)&lV[d*64 + pc*8];
        po[dt] = __builtin_amdgcn_mfma_f32_16x16x32_bf16(pf[ks], vf, po[dt], 0,0,0);
      }
    }
    __syncthreads();
  }
#pragma unroll
  for(int r=0;r<4;r++){
    float inv = 1.f / lrun[r];
    size_t orow = (size_t)(b*2048 + q0 + wave*16 + l4*4 + r);
#pragma unroll
    for(int dt=0;dt<8;dt++){
      ao[orow*2048 + hh*128 + dt*16 + l15] = f2b(po[dt][r]*inv);
    }
  }
}

// ---------------- SwiGLU: silu(gate)*x -> bf16 h ----------------
__global__ __launch_bounds__(256) void swiglu_kernel(const unsigned short* __restrict__ proj,
                                                     unsigned short* __restrict__ h){
  size_t idx = (size_t)blockIdx.x*256 + threadIdx.x;   // one 8-elem chunk each
  int row = (int)(idx >> 10);                          // 1024 chunks per row
  int c8  = (int)(idx & 1023);
  const unsigned short* pr = proj + (size_t)row*FOUT + 2304 + c8*8;
  ushort8 xv = *(const ushort8*)pr;
  ushort8 gv = *(const ushort8*)(pr + FFI);
  ushort8 ov;
#pragma unroll
  for(int e=0;e<8;e++){
    float xf = b2f(xv[e]);
    float gf = b2f(gv[e]);
    float sg = gf / (1.f + __expf(-gf));
    ov[e] = f2b(sg*xf);
  }
  *(ushort8*)(h + (size_t)row*FFI + c8*8) = ov;
}

extern "C" void kernel_launch(void* const* d_in, const int* in_sizes, int n_in,
                              void* d_out, int out_size, void* d_ws, size_t ws_size,
                              hipStream_t stream){
  const float* x     = (const float*)d_in[0];
  const float* gamma = (const float*)d_in[1];
  const float* Wf    = (const float*)d_in[2];
  const float* Wa    = (const float*)d_in[3];
  const float* Wff   = (const float*)d_in[4];
  float* out = (float*)d_out;

  char* p = (char*)d_ws;                       // ~356 MB total
  unsigned short* xn   = (unsigned short*)p;   p += (size_t)4096*2048*2;
  unsigned short* WfT  = (unsigned short*)p;   p += (size_t)18688*2048*2;
  unsigned short* proj = (unsigned short*)p;   p += (size_t)4096*18688*2;
  unsigned short* WaT  = (unsigned short*)p;   p += (size_t)2048*2048*2;
  unsigned short* WffT = (unsigned short*)p;   p += (size_t)2048*8192*2;
  unsigned short* vtb  = (unsigned short*)p;   p += (size_t)2*128*2048*2;
  unsigned short* aob  = (unsigned short*)p;   p += (size_t)4096*2048*2;
  unsigned short* hb   = (unsigned short*)p;   p += (size_t)4096*8192*2;

  ln_kernel<<<4096, 256, 0, stream>>>(x, gamma, xn);
  tcast_kernel<<<dim3(584,64),  dim3(32,8), 0, stream>>>(Wf,  WfT,  2048, 18688);
  tcast_kernel<<<dim3(64,64),   dim3(32,8), 0, stream>>>(Wa,  WaT,  2048, 2048);
  tcast_kernel<<<dim3(64,256),  dim3(32,8), 0, stream>>>(Wff, WffT, 8192, 2048);
  gemm_kernel<0><<<dim3(146,32), 256, 0, stream>>>(xn, WfT, proj, nullptr, 4096, 18688, 2048);
  rope_kernel<<<4096, 256, 0, stream>>>(proj);
  vtrans_kernel<<<dim3(64,4,2), dim3(32,8), 0, stream>>>(proj, vtb);
  attn_kernel<<<dim3(32,16,2), 256, 0, stream>>>(proj, vtb, aob);
  gemm_kernel<1><<<dim3(16,32), 256, 0, stream>>>(aob, WaT, nullptr, out, 4096, 2048, 2048);
  swiglu_kernel<<<16384, 256, 0, stream>>>(proj, hb);
  gemm_kernel<2><<<dim3(16,32), 256, 0, stream>>>(hb, WffT, nullptr, out, 4096, 2048, 8192);
}

// Round 2
// 903.330 us; speedup vs baseline: 1.2704x; 1.2704x over previous
//
#include <hip/hip_runtime.h>

typedef __attribute__((ext_vector_type(8))) short short8;
typedef __attribute__((ext_vector_type(4))) float floatx4;
typedef __attribute__((ext_vector_type(8))) unsigned short ushort8;

#define FOUT 18688
#define FFI  8192

__device__ __forceinline__ float b2f(unsigned short u){
  union { unsigned int i; float f; } v; v.i = ((unsigned int)u) << 16; return v.f;
}
__device__ __forceinline__ unsigned short f2b(float f){
  union { float f; unsigned int i; } v; v.f = f;
  unsigned int r = v.i + 0x7FFFu + ((v.i >> 16) & 1u);
  return (unsigned short)(r >> 16);
}
__device__ __forceinline__ void gld_lds16(const void* g, void* l){
  __builtin_amdgcn_global_load_lds((const __attribute__((address_space(1))) void*)g,
                                   (__attribute__((address_space(3))) void*)l, 16, 0, 0);
}

// ---------------- LayerNorm (fp32 in) -> bf16 xn ----------------
__global__ __launch_bounds__(256) void ln_kernel(const float* __restrict__ x,
                                                 const float* __restrict__ gamma,
                                                 unsigned short* __restrict__ xn){
  int row = blockIdx.x;
  const float* xr = x + (size_t)row * 2048;
  int tid = threadIdx.x;
  float v[8]; float s = 0.f, s2 = 0.f;
#pragma unroll
  for(int i=0;i<8;i++){ float t = xr[tid + i*256]; v[i]=t; s+=t; s2+=t*t; }
#pragma unroll
  for(int off=32; off>=1; off>>=1){ s += __shfl_down(s, off, 64); s2 += __shfl_down(s2, off, 64); }
  __shared__ float red[8];
  int wv = tid>>6, ln_ = tid&63;
  if(ln_==0){ red[wv] = s; red[wv+4] = s2; }
  __syncthreads();
  s  = red[0]+red[1]+red[2]+red[3];
  s2 = red[4]+red[5]+red[6]+red[7];
  float mu  = s * (1.f/2048.f);
  float var = s2 * (1.f/2048.f) - mu*mu;
  float rstd = rsqrtf(var + 1e-5f);
#pragma unroll
  for(int i=0;i<8;i++){
    float o = (v[i]-mu)*rstd*gamma[tid + i*256];
    xn[(size_t)row*2048 + tid + i*256] = f2b(o);
  }
}

// ---------------- fp32 RxC -> bf16 CxR transpose (weights) ----------------
__global__ void tcast_kernel(const float* __restrict__ W, unsigned short* __restrict__ Wt,
                             int R, int C){
  __shared__ float t[32][33];
  int bx = blockIdx.x*32, by = blockIdx.y*32;
  int tx = threadIdx.x, ty = threadIdx.y;
#pragma unroll
  for(int i=0;i<4;i++) t[ty+i*8][tx] = W[(size_t)(by+ty+i*8)*C + bx+tx];
  __syncthreads();
#pragma unroll
  for(int i=0;i<4;i++) Wt[(size_t)(bx+ty+i*8)*R + by+tx] = f2b(t[tx][ty+i*8]);
}

// ---------------- V slice of proj -> Vt[b][d][n] (bf16) ----------------
__global__ void vtrans_kernel(const unsigned short* __restrict__ proj, unsigned short* __restrict__ vt){
  __shared__ unsigned short t[32][33];
  int b = blockIdx.z;
  int n0 = blockIdx.x*32, d0 = blockIdx.y*32;
  int tx = threadIdx.x, ty = threadIdx.y;
#pragma unroll
  for(int i=0;i<4;i++) t[ty+i*8][tx] = proj[(size_t)(b*2048 + n0+ty+i*8)*FOUT + 2176 + d0+tx];
  __syncthreads();
#pragma unroll
  for(int i=0;i<4;i++) vt[((size_t)b*128 + d0+ty+i*8)*2048 + n0+tx] = t[tx][ty+i*8];
}

// ---------------- RoPE (xpos) in-place on q heads + k ----------------
__global__ __launch_bounds__(256) void rope_kernel(unsigned short* __restrict__ proj){
  int row = blockIdx.x;          // b*2048 + i
  int i = row & 2047;
  unsigned short* pr = proj + (size_t)row*FOUT;
  float fi = (float)i;
  float pw0 = (fi - 1024.f) * (1.f/512.f);
  for(int item = threadIdx.x; item < 17*64; item += 256){
    int slot = item >> 6;        // 0..15 = q head, 16 = k
    int j = item & 63;
    float fj = (float)j;
    float invf = powf(10000.f, -fj*(1.f/64.f));
    float p = fi * invf;
    float c = cosf(p), sn = sinf(p);
    float sv = (2.f*fj + 51.2f) * (1.f/179.2f);
    float pw = (slot==16) ? -pw0 : pw0;
    float scale = powf(sv, pw);
    int colbase = (slot<16) ? slot*128 : 2048;
    float x1 = b2f(pr[colbase+j]);
    float x2 = b2f(pr[colbase+j+64]);
    float cs = c*scale, ss = sn*scale;
    pr[colbase+j]    = f2b(x1*cs - x2*ss);
    pr[colbase+j+64] = f2b(x2*cs + x1*ss);
  }
}

// ================= 256x256 8-phase bf16 GEMM (T1+T2+T3+T4+T5) =================
// C(MxN) = A(MxK) * Bt(NxK)^T.  BK=64, 8 waves (2M x 4N), 128KiB LDS dbuf.
// Per tile: 4 phases (quadrants of 16 MFMA). Staging 1 half-tile/phase:
//  P1: A-h1(t+1) | P2: B-h0(t+2) | P3: B-h1(t+2) | P4: A-h0(t+2), then vmcnt(6).
// Every staged region's last LDS reader drained >=1 phase-barrier earlier.
// MODE 0: bf16 store. MODE 1: f32 store. MODE 2: f32 atomicAdd (split-K via blockIdx.z).
#define SCHED0() __builtin_amdgcn_sched_barrier(0)
#define BARR()   do{ SCHED0(); __builtin_amdgcn_s_barrier(); SCHED0(); }while(0)

template<int MODE>
__global__ __launch_bounds__(512, 2) void gemm8p_kernel(const unsigned short* __restrict__ A,
                                                        const unsigned short* __restrict__ Bt,
                                                        unsigned short* __restrict__ Cb,
                                                        float* __restrict__ Cf,
                                                        int N, int K, int NT, int ntn){
  __shared__ unsigned short lds[65536];   // [buf][A 16384 el | B 16384 el]
  const int tid = threadIdx.x;
  const int wave = tid>>6, lane = tid&63;
  const int l15 = lane&15, l4 = lane>>4;
  const int wr = wave>>2, wc = wave&3;    // 2(M) x 4(N)
  int id = blockIdx.x;
  int cpx = (int)gridDim.x >> 3;          // gridDim.x % 8 == 0 guaranteed
  int swz = (id & 7)*cpx + (id >> 3);
  int tm = swz / ntn, tn = swz - tm*ntn;
  int kbase = (int)blockIdx.z * (NT*64);
  const unsigned short* Ab = A  + (size_t)tm*256*K + kbase;
  const unsigned short* Bb = Bt + (size_t)tn*256*K + kbase;

  // staging geometry: thread covers slots tid and tid+512 of a 128x8-chunk half-tile
  const int r0 = tid>>3;
  const int colc = ((tid&7) ^ (r0&7))*8;  // pre-swizzled global chunk (row+64 keeps &7)
  const int dstw = wave*512;

#define STAGE(t_, h_, isB_) do{ \
    const unsigned short* g_ = (isB_) ? Bb : Ab; \
    int db_ = (((t_)&1)<<15) + ((isB_)<<14) + ((h_)<<13) + dstw; \
    gld_lds16(g_ + (size_t)((h_)*128 + r0)*K + (t_)*64 + colc, &lds[db_]); \
    gld_lds16(g_ + (size_t)((h_)*128 + r0 + 64)*K + (t_)*64 + colc, &lds[db_ + 4096]); \
  }while(0)

  // fragment read offsets (row&7 == l15&7 for all fragments)
  const int sw8 = l15&7;
  const int fo0 = ((l4    )^sw8)*8;
  const int fo1 = ((l4 + 4)^sw8)*8;
  const int albase = (wr*128 + l15)*64;
  const int blbase = 16384 + (wc*64 + l15)*64;

  floatx4 acc[8][4];
#pragma unroll
  for(int i=0;i<8;i++)
#pragma unroll
    for(int j=0;j<4;j++) acc[i][j] = (floatx4)0.f;

  // prologue: tile0 full + B(1) + A-h0(1); retire tile0, keep 3 half-tiles in flight
  STAGE(0,0,0); STAGE(0,1,0); STAGE(0,0,1); STAGE(0,1,1);
  STAGE(1,0,1); STAGE(1,1,1); STAGE(1,0,0);
  asm volatile("s_waitcnt vmcnt(6)" ::: "memory");
  BARR();

  short8 a_[8], b_[8];
  for(int t=0; t<NT; ++t){
    const int bufo = (t&1)<<15;
    // ---------- P1: read A(m0) + B(full); compute (m0,n0) ----------
#pragma unroll
    for(int mf=0; mf<4; mf++){
      a_[mf*2+0] = *(const short8*)&lds[bufo + albase + mf*1024 + fo0];
      a_[mf*2+1] = *(const short8*)&lds[bufo + albase + mf*1024 + fo1];
    }
#pragma unroll
    for(int nf=0; nf<4; nf++){
      b_[nf*2+0] = *(const short8*)&lds[bufo + blbase + nf*1024 + fo0];
      b_[nf*2+1] = *(const short8*)&lds[bufo + blbase + nf*1024 + fo1];
    }
    if(t+1 < NT) STAGE(t+1,1,0);
    BARR();
    asm volatile("s_waitcnt lgkmcnt(0)" ::: "memory");
    SCHED0();
    __builtin_amdgcn_s_setprio(1);
#pragma unroll
    for(int mf=0; mf<4; mf++)
#pragma unroll
      for(int nf=0; nf<2; nf++)
#pragma unroll
        for(int kk=0; kk<2; kk++)
          acc[mf][nf] = __builtin_amdgcn_mfma_f32_16x16x32_bf16(a_[mf*2+kk], b_[nf*2+kk], acc[mf][nf], 0,0,0);
    __builtin_amdgcn_s_setprio(0);
    BARR();
    // ---------- P2: compute (m0,n1) ----------
    if(t+2 < NT) STAGE(t+2,0,1);
    BARR();
    __builtin_amdgcn_s_setprio(1);
#pragma unroll
    for(int mf=0; mf<4; mf++)
#pragma unroll
      for(int nf=0; nf<2; nf++)
#pragma unroll
        for(int kk=0; kk<2; kk++)
          acc[mf][2+nf] = __builtin_amdgcn_mfma_f32_16x16x32_bf16(a_[mf*2+kk], b_[(2+nf)*2+kk], acc[mf][2+nf], 0,0,0);
    __builtin_amdgcn_s_setprio(0);
    BARR();
    // ---------- P3: read A(m1); compute (m1,n0) ----------
#pragma unroll
    for(int mf=0; mf<4; mf++){
      a_[mf*2+0] = *(const short8*)&lds[bufo + albase + 4096 + mf*1024 + fo0];
      a_[mf*2+1] = *(const short8*)&lds[bufo + albase + 4096 + mf*1024 + fo1];
    }
    if(t+2 < NT) STAGE(t+2,1,1);
    BARR();
    asm volatile("s_waitcnt lgkmcnt(0)" ::: "memory");
    SCHED0();
    __builtin_amdgcn_s_setprio(1);
#pragma unroll
    for(int mf=0; mf<4; mf++)
#pragma unroll
      for(int nf=0; nf<2; nf++)
#pragma unroll
        for(int kk=0; kk<2; kk++)
          acc[4+mf][nf] = __builtin_amdgcn_mfma_f32_16x16x32_bf16(a_[mf*2+kk], b_[nf*2+kk], acc[4+mf][nf], 0,0,0);
    __builtin_amdgcn_s_setprio(0);
    BARR();
    // ---------- P4: compute (m1,n1); boundary vmcnt ----------
    if(t+2 < NT) STAGE(t+2,0,0);
    BARR();
    __builtin_amdgcn_s_setprio(1);
#pragma unroll
    for(int mf=0; mf<4; mf++)
#pragma unroll
      for(int nf=0; nf<2; nf++)
#pragma unroll
        for(int kk=0; kk<2; kk++)
          acc[4+mf][2+nf] = __builtin_amdgcn_mfma_f32_16x16x32_bf16(a_[mf*2+kk], b_[(2+nf)*2+kk], acc[4+mf][2+nf], 0,0,0);
    __builtin_amdgcn_s_setprio(0);
    SCHED0();
    if(t+2 < NT){      asm volatile("s_waitcnt vmcnt(6)" ::: "memory"); }
    else if(t+1 < NT){ asm volatile("s_waitcnt vmcnt(0)" ::: "memory"); }
    BARR();
  }

  // epilogue
  const size_t crow0 = (size_t)tm*256 + wr*128 + l4*4;
  const size_t ccol0 = (size_t)tn*256 + wc*64 + l15;
#pragma unroll
  for(int mi=0; mi<8; mi++){
#pragma unroll
    for(int n=0; n<4; n++){
#pragma unroll
      for(int r=0; r<4; r++){
        size_t row = crow0 + (mi>>2)*64 + (mi&3)*16 + r;
        size_t col = ccol0 + n*16;
        float v = acc[mi][n][r];
        if(MODE==0)      Cb[row*N + col] = f2b(v);
        else if(MODE==1) Cf[row*N + col] = v;
        else             atomicAdd(&Cf[row*N + col], v);
      }
    }
  }
}

// ---------------- flash causal attention (MQA: shared K/V) ----------------
__global__ __launch_bounds__(256) void attn_kernel(const unsigned short* __restrict__ proj,
                                                   const unsigned short* __restrict__ vt,
                                                   unsigned short* __restrict__ ao){
  __shared__ unsigned short lK[64*128];   // [key][d], chunk-swizzled
  __shared__ unsigned short lV[128*64];   // [d][key], chunk-swizzled
  __shared__ unsigned short lP[4*16*64];  // per-wave P, chunk-swizzled
  int qt = blockIdx.x, hh = blockIdx.y, b = blockIdx.z;
  int tid = threadIdx.x, wave = tid>>6, lane = tid&63;
  int l15 = lane&15, l4 = lane>>4;
  int q0 = qt*64;
  int qrow = q0 + wave*16 + l15;
  const unsigned short* qp = proj + (size_t)(b*2048 + qrow)*FOUT + hh*128 + l4*8;
  short8 qf[4];
#pragma unroll
  for(int ds=0; ds<4; ds++) qf[ds] = *(const short8*)(qp + ds*32);
  floatx4 po[8];
#pragma unroll
  for(int dt=0; dt<8; dt++) po[dt] = (floatx4)0.f;
  float mrun[4] = {-1e30f,-1e30f,-1e30f,-1e30f};
  float lrun[4] = {0.f,0.f,0.f,0.f};
  unsigned short* lPw = lP + wave*1024;
  const unsigned short* kb = proj + (size_t)(b*2048)*FOUT + 2048;
  const unsigned short* vb = vt + (size_t)b*128*2048;

  for(int kv=0; kv<=qt; kv++){
    int kv0 = kv*64;
#pragma unroll
    for(int it=0; it<4; it++){
      int f = it*256 + tid;
      int r = f>>4, pc = f&15;
      int gc = pc ^ (r&7);
      gld_lds16(kb + (size_t)(kv0 + r)*FOUT + gc*8, &lK[(it*256 + wave*64)*8]);
    }
#pragma unroll
    for(int it=0; it<4; it++){
      int f = it*256 + tid;
      int d = f>>3, pc = f&7;
      int gc = pc ^ (d&7);
      gld_lds16(vb + (size_t)d*2048 + kv0 + gc*8, &lV[(it*256 + wave*64)*8]);
    }
    __syncthreads();
    floatx4 sa[4];
#pragma unroll
    for(int jt=0;jt<4;jt++) sa[jt] = (floatx4)0.f;
#pragma unroll
    for(int jt=0;jt<4;jt++){
      int krow = jt*16 + l15;
#pragma unroll
      for(int ds=0; ds<4; ds++){
        int pc = (l4 + ds*4) ^ (krow&7);
        short8 kf = *(const short8*)&lK[krow*128 + pc*8];
        sa[jt] = __builtin_amdgcn_mfma_f32_16x16x32_bf16(qf[ds], kf, sa[jt], 0,0,0);
      }
    }
    float pv[4][4];
    bool diag = (kv == qt);
#pragma unroll
    for(int jt=0;jt<4;jt++){
#pragma unroll
      for(int r=0;r<4;r++){
        float s = sa[jt][r] * 0.08838834764831843f;
        if(diag && (kv0 + jt*16 + l15 > q0 + wave*16 + l4*4 + r)) s = -1e30f;
        pv[jt][r] = s;
      }
    }
    float mnew[4], corr[4];
#pragma unroll
    for(int r=0;r<4;r++){
      float mx = fmaxf(fmaxf(pv[0][r],pv[1][r]),fmaxf(pv[2][r],pv[3][r]));
      mx = fmaxf(mx, __shfl_xor(mx, 1, 64));
      mx = fmaxf(mx, __shfl_xor(mx, 2, 64));
      mx = fmaxf(mx, __shfl_xor(mx, 4, 64));
      mx = fmaxf(mx, __shfl_xor(mx, 8, 64));
      float mn = fmaxf(mrun[r], mx);
      corr[r] = __expf(mrun[r] - mn);
      mrun[r] = mn;
      mnew[r] = mn;
    }
    float rsum[4] = {0.f,0.f,0.f,0.f};
#pragma unroll
    for(int jt=0;jt<4;jt++){
#pragma unroll
      for(int r=0;r<4;r++){
        float p = __expf(pv[jt][r] - mnew[r]);
        pv[jt][r] = p;
        rsum[r] += p;
      }
    }
#pragma unroll
    for(int r=0;r<4;r++){
      float rs = rsum[r];
      rs += __shfl_xor(rs, 1, 64);
      rs += __shfl_xor(rs, 2, 64);
      rs += __shfl_xor(rs, 4, 64);
      rs += __shfl_xor(rs, 8, 64);
      lrun[r] = lrun[r]*corr[r] + rs;
    }
#pragma unroll
    for(int dt=0;dt<8;dt++){
#pragma unroll
      for(int r=0;r<4;r++) po[dt][r] *= corr[r];
    }
#pragma unroll
    for(int jt=0;jt<4;jt++){
#pragma unroll
      for(int r=0;r<4;r++){
        int i_ = l4*4 + r;
        int j = jt*16 + l15;
        int pc = (j>>3) ^ (i_&7);
        lPw[i_*64 + pc*8 + (j&7)] = f2b(pv[jt][r]);
      }
    }
    asm volatile("s_waitcnt lgkmcnt(0)" ::: "memory");
    short8 pf[2];
#pragma unroll
    for(int ks=0;ks<2;ks++){
      int pc = (l4 + ks*4) ^ (l15&7);
      pf[ks] = *(const short8*)&lPw[l15*64 + pc*8];
    }
#pragma unroll
    for(int dt=0;dt<8;dt++){
      int d = dt*16 + l15;
#pragma unroll
      for(int ks=0;ks<2;ks++){
        int pc = (ks*4 + l4) ^ (d&7);
        short8 vf = *(const short8*)&lV[d*64 + pc*8];
        po[dt] = __builtin_amdgcn_mfma_f32_16x16x32_bf16(pf[ks], vf, po[dt], 0,0,0);
      }
    }
    __syncthreads();
  }
#pragma unroll
  for(int r=0;r<4;r++){
    float inv = 1.f / lrun[r];
    size_t orow = (size_t)(b*2048 + q0 + wave*16 + l4*4 + r);
#pragma unroll
    for(int dt=0;dt<8;dt++){
      ao[orow*2048 + hh*128 + dt*16 + l15] = f2b(po[dt][r]*inv);
    }
  }
}

// ---------------- SwiGLU: silu(gate)*x -> bf16 h ----------------
__global__ __launch_bounds__(256) void swiglu_kernel(const unsigned short* __restrict__ proj,
                                                     unsigned short* __restrict__ h){
  size_t idx = (size_t)blockIdx.x*256 + threadIdx.x;
  int row = (int)(idx >> 10);
  int c8  = (int)(idx & 1023);
  const unsigned short* pr = proj + (size_t)row*FOUT + 2304 + c8*8;
  ushort8 xv = *(const ushort8*)pr;
  ushort8 gv = *(const ushort8*)(pr + FFI);
  ushort8 ov;
#pragma unroll
  for(int e=0;e<8;e++){
    float xf = b2f(xv[e]);
    float gf = b2f(gv[e]);
    float sg = gf / (1.f + __expf(-gf));
    ov[e] = f2b(sg*xf);
  }
  *(ushort8*)(h + (size_t)row*FFI + c8*8) = ov;
}

extern "C" void kernel_launch(void* const* d_in, const int* in_sizes, int n_in,
                              void* d_out, int out_size, void* d_ws, size_t ws_size,
                              hipStream_t stream){
  const float* x     = (const float*)d_in[0];
  const float* gamma = (const float*)d_in[1];
  const float* Wf    = (const float*)d_in[2];
  const float* Wa    = (const float*)d_in[3];
  const float* Wff   = (const float*)d_in[4];
  float* out = (float*)d_out;

  char* p = (char*)d_ws;
  unsigned short* xn   = (unsigned short*)p;   p += (size_t)4096*2048*2;
  unsigned short* WfT  = (unsigned short*)p;   p += (size_t)18688*2048*2;
  unsigned short* proj = (unsigned short*)p;   p += (size_t)4096*18688*2;
  unsigned short* WaT  = (unsigned short*)p;   p += (size_t)2048*2048*2;
  unsigned short* WffT = (unsigned short*)p;   p += (size_t)2048*8192*2;
  unsigned short* vtb  = (unsigned short*)p;   p += (size_t)2*128*2048*2;
  unsigned short* aob  = (unsigned short*)p;   p += (size_t)4096*2048*2;
  unsigned short* hb   = (unsigned short*)p;   p += (size_t)4096*8192*2;

  ln_kernel<<<4096, 256, 0, stream>>>(x, gamma, xn);
  tcast_kernel<<<dim3(584,64),  dim3(32,8), 0, stream>>>(Wf,  WfT,  2048, 18688);
  tcast_kernel<<<dim3(64,64),   dim3(32,8), 0, stream>>>(Wa,  WaT,  2048, 2048);
  tcast_kernel<<<dim3(64,256),  dim3(32,8), 0, stream>>>(Wff, WffT, 8192, 2048);
  // GEMM1: proj = xn @ WfT^T   (4096 x 18688 x 2048), 16x73 tiles
  gemm8p_kernel<0><<<dim3(1168,1,1), 512, 0, stream>>>(xn, WfT, proj, nullptr, 18688, 2048, 32, 73);
  rope_kernel<<<4096, 256, 0, stream>>>(proj);
  vtrans_kernel<<<dim3(64,4,2), dim3(32,8), 0, stream>>>(proj, vtb);
  attn_kernel<<<dim3(32,16,2), 256, 0, stream>>>(proj, vtb, aob);
  // GEMM2: out = aob @ WaT^T   (4096 x 2048 x 2048), 16x8 tiles
  gemm8p_kernel<1><<<dim3(128,1,1), 512, 0, stream>>>(aob, WaT, nullptr, out, 2048, 2048, 32, 8);
  swiglu_kernel<<<16384, 256, 0, stream>>>(proj, hb);
  // GEMM3: out += hb @ WffT^T  (4096 x 2048 x 8192), split-K=2, atomic f32
  gemm8p_kernel<2><<<dim3(128,1,2), 512, 0, stream>>>(hb, WffT, nullptr, out, 2048, 8192, 64, 8);
}